// Round 8
// baseline (275.103 us; speedup 1.0000x reference)
//
#include <hip/hip_runtime.h>

#define N_NODES 50000
#define N_EDGES 800000
#define NCHUNK 128
#define NRANGE 4
#define RNODES (N_NODES / NRANGE)         // 12500 (hist ranges)
#define CEDGES (N_EDGES / NCHUNK)         // 6250
#define HIST_NB (NCHUNK * NRANGE)         // 512
#define FRANGE 8
#define RN (N_NODES / FRANGE)             // 6250 (fill ranges)
#define FILL_NB (NCHUNK * FRANGE)         // 1024
#define SCAN_NB 782                       // 64-node scan blocks
#define NBLK 782                          // 64-row GEMM tiles

typedef __attribute__((ext_vector_type(8))) short short8;
typedef __attribute__((ext_vector_type(4))) float f32x4;

struct LPtrs { const float *W1, *W2, *W3, *Wl, *b1, *b3, *bl; };
struct AllPtrs { LPtrs l[3]; };

__device__ inline unsigned short f2b(float f) {
    union { float f; unsigned u; } c; c.f = f;
    return (unsigned short)((c.u + 0x7FFFu + ((c.u >> 16) & 1u)) >> 16);
}
__device__ inline float b2f(unsigned short h) {
    union { unsigned u; float f; } c; c.u = ((unsigned)h) << 16;
    return c.f;
}

// ---------------------------------------------------------------------------
// K1 (fused): blocks 0..511 partial histograms (packed-u8 LDS atomics);
// blocks 512..547 pack Wml = Wm@Wl into B-frag bf16 + bias rows.
__global__ __launch_bounds__(256) void histpack_kernel(const int* __restrict__ dst,
                                                       unsigned char* __restrict__ hist_part,
                                                       AllPtrs ap,
                                                       unsigned short* __restrict__ Wp,
                                                       float* __restrict__ rows) {
    __shared__ unsigned int h[5248];          // 21 KB
    const int t = threadIdx.x;
    if (blockIdx.x < HIST_NB) {
        const int chunk = blockIdx.x >> 2;
        const int range = blockIdx.x & 3;
        const int nbase = range * RNODES;
        for (int i = t; i < RNODES / 4; i += 256) h[i] = 0u;
        __syncthreads();
        const int* dp = dst + chunk * CEDGES;
        for (int i = t; i < CEDGES; i += 256) {
            int d = dp[i] - nbase;
            if ((unsigned)d < (unsigned)RNODES)
                atomicAdd(&h[d >> 2], 1u << ((d & 3) * 8));
        }
        __syncthreads();
        unsigned int* out = (unsigned int*)(hist_part + (long)chunk * N_NODES + nbase);
        for (int i = t; i < RNODES / 4; i += 256) out[i] = h[i];
    } else {
        float* sW = (float*)h;                // 64x65
        float* sL = (float*)h + 64 * 65;      // 64x17
        const int wi = blockIdx.x - HIST_NB;
        const int layer = wi / 12;
        const int ct = wi % 12;
        LPtrs L = ap.l[layer];
        const float* Wm = (ct < 4) ? L.W1 : (ct < 8) ? L.W2 : L.W3;
        const int colb = (ct & 3) * 16;
        for (int i = t; i < 64 * 64; i += 256) sW[(i >> 6) * 65 + (i & 63)] = Wm[i];
        for (int i = t; i < 64 * 16; i += 256) {
            int q = i >> 4, c = i & 15;
            sL[q * 17 + c] = L.Wl[q * 64 + colb + c];
        }
        __syncthreads();
        for (int local = t; local < 1024; local += 256) {
            int j = local & 7, lane = (local >> 3) & 63, s = local >> 9;
            int k = s * 32 + (lane >> 4) * 8 + j;
            int c = lane & 15;
            float acc = 0.f;
            #pragma unroll 8
            for (int q = 0; q < 64; ++q) acc += sW[k * 65 + q] * sL[q * 17 + c];
            Wp[layer * 12288 + ct * 1024 + local] = f2b(acc);
        }
        if (ct == 0 && t < 64) {
            int col = t;
            float r1 = 0.f, r3 = 0.f;
            for (int q = 0; q < 64; ++q) {
                float wl = L.Wl[q * 64 + col];
                r1 += L.b1[q] * wl;
                r3 += L.b3[q] * wl;
            }
            rows[layer * 128 + col] = r1;
            rows[layer * 128 + 64 + col] = r3 + L.bl[col];
        }
    }
}

// ---------------------------------------------------------------------------
// K2: per-node exclusive scan across 128 chunks, 4 threads/node (32
// independent u8 loads each). 64 nodes/block, 782 blocks.
__global__ __launch_bounds__(256) void scanA2_kernel(unsigned char* __restrict__ hist_part,
                                                     int* __restrict__ off,
                                                     int* __restrict__ deg,
                                                     int* __restrict__ bsum) {
    __shared__ int part[4][64];
    const int t = threadIdx.x;
    const int ln = t & 63;
    const int cg = t >> 6;
    const int node = blockIdx.x * 64 + ln;
    unsigned char* col = hist_part + node;
    unsigned char v[32];
    int s = 0;
    if (node < N_NODES) {
        #pragma unroll
        for (int k = 0; k < 32; ++k) {
            v[k] = col[(long)(cg * 32 + k) * N_NODES];
            s += v[k];
        }
    }
    part[cg][ln] = s;
    __syncthreads();
    int run = 0, tot = 0;
    #pragma unroll
    for (int g = 0; g < 4; ++g) {
        int p = part[g][ln];
        if (g < cg) run += p;
        tot += p;
    }
    if (node < N_NODES) {
        #pragma unroll
        for (int k = 0; k < 32; ++k) {
            col[(long)(cg * 32 + k) * N_NODES] = (unsigned char)run;
            run += v[k];
        }
    }
    if (cg == 0) {
        if (node < N_NODES) deg[node] = tot;
        int x = tot;
        #pragma unroll
        for (int d = 1; d < 64; d <<= 1) {
            int u = __shfl_up(x, d, 64);
            if (ln >= d) x += u;
        }
        if (node < N_NODES) off[node] = x - tot;
        if (ln == 63) bsum[blockIdx.x] = x;
    }
}

// ---------------------------------------------------------------------------
// K3: fill csr. FRANGE=8 node-ranges -> 25 KB cursor + 4 KB scan = 29 KB LDS
// (5 blocks/CU vs 2 at the old 54 KB — the R7 counter showed fillp at 15%
// occupancy / 5% VALU: pure latency starvation). 1024 blocks. bsum[782]
// scan folded in; chunk-0 blocks publish rowinfo = {abs beg, deg}.
__global__ __launch_bounds__(256) void fillp_kernel(
    const int* __restrict__ src, const int* __restrict__ dst,
    const int* __restrict__ off, const int* __restrict__ bsum,
    const unsigned char* __restrict__ hist_part,
    int* __restrict__ csr, int2* __restrict__ rowinfo,
    const int* __restrict__ deg)
{
    __shared__ int cur[RN];                   // 25 KB (scan reuses first 256)
    __shared__ int sb[1024];                  // 4 KB
    const int t = threadIdx.x;

    const int i0 = t * 4;
    int a0 = (i0 + 0 < SCAN_NB) ? bsum[i0 + 0] : 0;
    int a1 = (i0 + 1 < SCAN_NB) ? bsum[i0 + 1] : 0;
    int a2 = (i0 + 2 < SCAN_NB) ? bsum[i0 + 2] : 0;
    int a3 = (i0 + 3 < SCAN_NB) ? bsum[i0 + 3] : 0;
    int s = a0 + a1 + a2 + a3;
    cur[t] = s;
    __syncthreads();
    #pragma unroll
    for (int d = 1; d < 256; d <<= 1) {
        int u = (t >= d) ? cur[t - d] : 0;
        __syncthreads();
        cur[t] += u;
        __syncthreads();
    }
    int excl = cur[t] - s;
    sb[i0 + 0] = excl;
    sb[i0 + 1] = excl + a0;
    sb[i0 + 2] = excl + a0 + a1;
    sb[i0 + 3] = excl + a0 + a1 + a2;
    __syncthreads();

    const int chunk = blockIdx.x >> 3;        // 128 chunks
    const int range = blockIdx.x & 7;         // 8 fill ranges
    const int nbase = range * RN;
    const unsigned char* bp = hist_part + (long)chunk * N_NODES + nbase;
    const int* op = off + nbase;
    for (int i = t; i < RN; i += 256) {
        int c = op[i] + sb[(nbase + i) >> 6] + (int)bp[i];
        cur[i] = c;
        if (chunk == 0)                       // bp==0 here: c = absolute row beg
            rowinfo[nbase + i] = make_int2(c, deg[nbase + i]);
    }
    __syncthreads();
    const int* dp = dst + chunk * CEDGES;
    const int* sp = src + chunk * CEDGES;
    for (int i = t; i < CEDGES; i += 256) {
        int d = dp[i] - nbase;
        if ((unsigned)d < (unsigned)RN) {
            int pos = atomicAdd(&cur[d], 1);
            csr[pos] = sp[i];
        }
    }
}

// ---------------------------------------------------------------------------
// K4: per-layer GEMM: a' = h@W1l; w = h@W3l - deg*((h@W2l) - row1) + row3.
// hf32 != null (layer 0): read fp32 x, cast in-register.
__global__ __launch_bounds__(256) void gemm3w_kernel(
    const unsigned short* __restrict__ hbf, const float* __restrict__ hf32,
    const unsigned short* __restrict__ Wp,
    const int* __restrict__ deg, const float* __restrict__ rows,
    unsigned short* __restrict__ abf, unsigned short* __restrict__ wbf)
{
    const int t = threadIdx.x;
    const int lane = t & 63;
    const int quad = lane >> 4, lm = lane & 15;
    const int row_base = blockIdx.x * 64 + (t >> 6) * 16;

    int arow = min(row_base + lm, N_NODES - 1);
    short8 a0, a1;
    if (hf32) {
        const float* hrow = hf32 + (long)arow * 64;
        #pragma unroll
        for (int j = 0; j < 8; ++j) {
            a0[j] = (short)f2b(hrow[quad * 8 + j]);
            a1[j] = (short)f2b(hrow[32 + quad * 8 + j]);
        }
    } else {
        const unsigned short* hrow = hbf + (long)arow * 64;
        a0 = *(const short8*)(hrow + quad * 8);
        a1 = *(const short8*)(hrow + 32 + quad * 8);
    }

    const short8* wp = (const short8*)Wp;
    f32x4 acc[12];
    #pragma unroll
    for (int ct = 0; ct < 12; ++ct) {
        f32x4 z = {0.f, 0.f, 0.f, 0.f};
        short8 w0 = wp[(ct * 2 + 0) * 64 + lane];
        short8 w1 = wp[(ct * 2 + 1) * 64 + lane];
        z = __builtin_amdgcn_mfma_f32_16x16x32_bf16(a0, w0, z, 0, 0, 0);
        z = __builtin_amdgcn_mfma_f32_16x16x32_bf16(a1, w1, z, 0, 0, 0);
        acc[ct] = z;
    }

    const int g0 = row_base + quad * 4;
    float dg[4];
    #pragma unroll
    for (int r = 0; r < 4; ++r) dg[r] = (float)deg[min(g0 + r, N_NODES - 1)];

    #pragma unroll
    for (int ct = 0; ct < 4; ++ct) {
        int col = ct * 16 + lm;
        float r1 = rows[col];
        float r3 = rows[64 + col];
        #pragma unroll
        for (int r = 0; r < 4; ++r) {
            int g = g0 + r;
            if (g < N_NODES) {
                abf[(long)g * 64 + col] = f2b(acc[ct][r]);
                float wv = acc[8 + ct][r] - dg[r] * (acc[4 + ct][r] - r1) + r3;
                wbf[(long)g * 64 + col] = f2b(wv);
            }
        }
    }
}

// ---------------------------------------------------------------------------
// K5: CSR gather + output. One wave per node; 8 edge slots x 8 lanes x 16B
// (short8) — half the VMEM instructions of the 8B variant, same cache
// lines, 8 rows outstanding per wave. out = relu(S' + w).
__global__ __launch_bounds__(256) void gather_out_kernel(
    const int2* __restrict__ rowinfo, const int* __restrict__ csr,
    const unsigned short* __restrict__ abf,
    const unsigned short* __restrict__ wbf,
    float* __restrict__ out_f, unsigned short* __restrict__ out_b, int last)
{
    int node = blockIdx.x * 4 + (threadIdx.x >> 6);
    int lane = threadIdx.x & 63;
    const int g = lane >> 3;                  // edge slot 0..7
    const int f = (lane & 7) * 8;             // feature octet
    int2 ri = rowinfo[node];
    int beg = ri.x;
    int end = beg + ri.y;
    float a[8] = {0.f, 0.f, 0.f, 0.f, 0.f, 0.f, 0.f, 0.f};
    int j = beg;
    for (; j + 8 <= end; j += 8) {
        int s = csr[j + g];
        short8 v = *(const short8*)(abf + (long)s * 64 + f);
        #pragma unroll
        for (int k = 0; k < 8; ++k) a[k] += b2f((unsigned short)v[k]);
    }
    if (j + g < end) {
        int s = csr[j + g];
        short8 v = *(const short8*)(abf + (long)s * 64 + f);
        #pragma unroll
        for (int k = 0; k < 8; ++k) a[k] += b2f((unsigned short)v[k]);
    }
    #pragma unroll
    for (int m = 8; m < 64; m <<= 1) {
        #pragma unroll
        for (int k = 0; k < 8; ++k) a[k] += __shfl_xor(a[k], m, 64);
    }
    if (g == 0) {
        short8 wv = *(const short8*)(wbf + (long)node * 64 + f);
        float o[8];
        #pragma unroll
        for (int k = 0; k < 8; ++k)
            o[k] = fmaxf(a[k] + b2f((unsigned short)wv[k]), 0.f);
        if (last) {
            float4 o0 = {o[0], o[1], o[2], o[3]};
            float4 o1 = {o[4], o[5], o[6], o[7]};
            *(float4*)(out_f + (long)node * 64 + f) = o0;
            *(float4*)(out_f + (long)node * 64 + f + 4) = o1;
        } else {
            short8 ob;
            #pragma unroll
            for (int k = 0; k < 8; ++k) ob[k] = (short)f2b(o[k]);
            *(short8*)(out_b + (long)node * 64 + f) = ob;
        }
    }
}

// ---------------------------------------------------------------------------
extern "C" void kernel_launch(void* const* d_in, const int* in_sizes, int n_in,
                              void* d_out, int out_size, void* d_ws, size_t ws_size,
                              hipStream_t stream) {
    const float* x  = (const float*)d_in[0];
    const int*   ei = (const int*)d_in[1];
    const int*   src = ei;
    const int*   dst = ei + N_EDGES;

    char* wsb = (char*)d_ws;
    unsigned char*  hist_part = (unsigned char*)(wsb);          // 6.4 MB (u8)
    unsigned short* abf  = (unsigned short*)(wsb + 6500000);    // 6.4 MB
    unsigned short* wbf  = (unsigned short*)(wsb + 12900000);   // 6.4 MB
    unsigned short* h1   = (unsigned short*)(wsb + 19300000);   // 6.4 MB
    unsigned short* Wp   = (unsigned short*)(wsb + 25700000);   // 72 KB
    float*          rows = (float*)(wsb + 25800000);            // 1.5 KB
    int*  off     = (int*)(wsb + 25900000);                     // N_NODES
    int*  deg     = (int*)(wsb + 26200000);                     // N_NODES
    int*  bsum    = (int*)(wsb + 26500000);                     // 1024
    int2* rowinfo = (int2*)(wsb + 26600000);                    // N_NODES int2
    int*  csr     = (int*)(wsb + 27100000);                     // N_EDGES

    AllPtrs ap;
    for (int l = 0; l < 3; ++l) {
        int base = 2 + l * 7;
        ap.l[l].W1 = (const float*)d_in[base + 0];
        ap.l[l].b1 = (const float*)d_in[base + 1];
        ap.l[l].W2 = (const float*)d_in[base + 2];
        ap.l[l].W3 = (const float*)d_in[base + 3];
        ap.l[l].b3 = (const float*)d_in[base + 4];
        ap.l[l].Wl = (const float*)d_in[base + 5];
        ap.l[l].bl = (const float*)d_in[base + 6];
    }

    // ---- CSR build + weight pack (R0 architecture) ----
    histpack_kernel<<<HIST_NB + 36, 256, 0, stream>>>(dst, hist_part, ap, Wp, rows);
    scanA2_kernel<<<SCAN_NB, 256, 0, stream>>>(hist_part, off, deg, bsum);
    fillp_kernel<<<FILL_NB, 256, 0, stream>>>(src, dst, off, bsum, hist_part,
                                              csr, rowinfo, deg);

    // ---- 3 layers: gemm -> gather (R0 shape, no fusion) ----
    const unsigned short* hin = nullptr;     // layer 0 reads x directly
    for (int l = 0; l < 3; ++l) {
        gemm3w_kernel<<<NBLK, 256, 0, stream>>>(
            hin, (l == 0) ? x : nullptr, Wp + l * 12288, deg, rows + l * 128,
            abf, wbf);
        gather_out_kernel<<<N_NODES / 4, 256, 0, stream>>>(
            rowinfo, csr, abf, wbf, (float*)d_out, h1, (l == 2));
        hin = h1;
    }
}